// Round 1
// baseline (355.196 us; speedup 1.0000x reference)
//
#include <hip/hip_runtime.h>

// Problem constants (fixed by setup_inputs)
#define BB   4
#define TT   300
#define NN   200
#define NINN 100
#define KK   10
#define DECAY 0.8f
#define THR   0.6f
#define DAMP  0.3f
#define REGC  300.0f
#define NREF  5

// ws layout (floats): xbar[B*T*NIN] | zfilt[B*T*N] | cbuf[B*T*N]
#define XBAR_OFF  0
#define ZFILT_OFF (BB*TT*NINN)
#define CBUF_OFF  (ZFILT_OFF + BB*TT*NN)

// ---------------------------------------------------------------------------
// Kernel 1: all time scans, one thread per (batch, channel).
//   tid < B*NIN          : x_bar forward scan
//   tid in [B*NIN, +B*N) : z_filt + refractory/post forward scan, then
//                          reverse scan producing c[b,t,j] in-place.
// No inter-thread deps: each thread reads/writes only its own channel.
// ---------------------------------------------------------------------------
__global__ void scan_kernel(const float* __restrict__ v,
                            const float* __restrict__ z,
                            const float* __restrict__ x,
                            const float* __restrict__ error1,
                            const float* __restrict__ error2,
                            const float* __restrict__ w_out,
                            float* __restrict__ ws) {
    int tid = blockIdx.x * blockDim.x + threadIdx.x;
    float* xbar  = ws + XBAR_OFF;
    float* zfilt = ws + ZFILT_OFF;
    float* cbuf  = ws + CBUF_OFF;

    if (tid < BB * NINN) {
        // x_bar[b,t,i] = 0.8*x_bar[b,t-1,i] + x[b,t,i]
        int b = tid / NINN, i = tid % NINN;
        float acc = 0.f;
        for (int t = 0; t < TT; ++t) {
            int idx = (b * TT + t) * NINN + i;
            acc = DECAY * acc + x[idx];
            xbar[idx] = acc;
        }
    } else if (tid < BB * NINN + BB * NN) {
        int u = tid - BB * NINN;
        int b = u / NN, j = u % NN;

        // ---- forward: z_filt, refractory count -> post_term (into cbuf) ----
        float zf = 0.f;
        int ref = 0;  // ref count valid for current t; ref[0]=0
        for (int t = 0; t < TT; ++t) {
            int idx = (b * TT + t) * NN + j;
            float zv = z[idx];
            float vv = v[idx];
            float vs = (vv - THR) / THR;
            float psi = (DAMP / THR) * fmaxf(1.f - fabsf(vs), 0.f);
            cbuf[idx] = (ref > 0) ? 0.f : psi;   // post_term
            zf = DECAY * zf + zv;
            zfilt[idx] = zf;
            // ref for t+1 depends on z[t] and ref[t]
            ref = (zv > 0.f) ? (NREF - 1) : (ref > 0 ? ref - 1 : 0);
        }

        // ---- reverse: G[t] = L[t] + 0.8*G[t+1]; c = post*(G + coeff) ----
        float wj[KK];
        #pragma unroll
        for (int k = 0; k < KK; ++k) wj[k] = w_out[j * KK + k];
        float coeff = (REGC / (float)(BB * TT)) * error2[j];
        float G = 0.f;
        for (int t = TT - 1; t >= 0; --t) {
            int bt = b * TT + t;
            float L = 0.f;
            #pragma unroll
            for (int k = 0; k < KK; ++k) L += error1[bt * KK + k] * wj[k];
            G = DECAY * G + L;
            int idx = bt * NN + j;
            cbuf[idx] = cbuf[idx] * (G + coeff);
        }
    }
}

// ---------------------------------------------------------------------------
// Kernel 2: output contractions over bt = B*T = 1200.
//   tid < 300*N        : O[p,j];  p<NIN -> dw_in[p,j] = sum xbar*c
//                        p>=NIN  -> dw_rec[i,j] = sum zbar*c (zbar = zfilt@t-1)
//   next N*K threads   : dw_out[j,k] = sum zfilt*error1
// c reads coalesced across j (fastest index); pre-trace reads broadcast.
// ---------------------------------------------------------------------------
__global__ void out_kernel(const float* __restrict__ error1,
                           const float* __restrict__ ws,
                           float* __restrict__ out) {
    int tid = blockIdx.x * blockDim.x + threadIdx.x;
    const float* xbar  = ws + XBAR_OFF;
    const float* zfilt = ws + ZFILT_OFF;
    const float* cbuf  = ws + CBUF_OFF;

    if (tid < (NINN + NN) * NN) {
        int p = tid / NN, j = tid % NN;
        float acc = 0.f;
        if (p < NINN) {
            #pragma unroll 4
            for (int bt = 0; bt < BB * TT; ++bt)
                acc += xbar[bt * NINN + p] * cbuf[bt * NN + j];
            out[p * NN + j] = acc;
        } else {
            int i = p - NINN;
            if (i == j) {               // autapse mask
                out[NINN * NN + i * NN + j] = 0.f;
                return;
            }
            for (int b = 0; b < BB; ++b) {
                #pragma unroll 4
                for (int t = 1; t < TT; ++t)
                    acc += zfilt[(b * TT + t - 1) * NN + i] * cbuf[(b * TT + t) * NN + j];
            }
            out[NINN * NN + i * NN + j] = acc;
        }
    } else if (tid < (NINN + NN) * NN + NN * KK) {
        int u = tid - (NINN + NN) * NN;
        int j = u / KK, k = u % KK;
        float acc = 0.f;
        #pragma unroll 4
        for (int bt = 0; bt < BB * TT; ++bt)
            acc += zfilt[bt * NN + j] * error1[bt * KK + k];
        out[NINN * NN + NN * NN + j * KK + k] = acc;
    }
}

extern "C" void kernel_launch(void* const* d_in, const int* in_sizes, int n_in,
                              void* d_out, int out_size, void* d_ws, size_t ws_size,
                              hipStream_t stream) {
    const float* v  = (const float*)d_in[0];
    const float* z  = (const float*)d_in[1];
    const float* x  = (const float*)d_in[2];
    const float* e1 = (const float*)d_in[3];
    const float* e2 = (const float*)d_in[4];
    const float* wo = (const float*)d_in[5];
    float* out = (float*)d_out;
    float* ws  = (float*)d_ws;

    // Kernel 1: B*NIN + B*N = 1200 scan threads
    scan_kernel<<<(BB * NINN + BB * NN + 255) / 256, 256, 0, stream>>>(
        v, z, x, e1, e2, wo, ws);

    // Kernel 2: (NIN+N)*N + N*K = 62000 output threads
    int total = (NINN + NN) * NN + NN * KK;
    out_kernel<<<(total + 255) / 256, 256, 0, stream>>>(e1, ws, out);
}

// Round 2
// 146.655 us; speedup vs baseline: 2.4220x; 2.4220x over previous
//
#include <hip/hip_runtime.h>

// Problem constants (fixed by setup_inputs)
#define BB    4
#define TT    300
#define NN    200
#define NINN  100
#define KK    10
#define DECAY 0.8f
#define THR   0.6f
#define DAMP  0.3f
#define REGC  300.0f

// Scan chunking: each thread owns LCH time steps of one (b, channel),
// warm-started with a WARM-step lookback (0.8^64 * 5 ~ 3e-6 — exact to fp32 noise).
#define LCH   30
#define NCHK  (TT / LCH)     // 10 chunks per (b, channel)
#define WARM  64

// Contraction split-K: bt = 1200 split into SKC chunks of KCH.
#define SKC   12
#define KCH   (BB * TT / SKC)  // 100

// ws layout (floats)
#define XBAR_OFF  0
#define ZFILT_OFF (BB*TT*NINN)                  // 120000
#define ZBAR_OFF  (ZFILT_OFF + BB*TT*NN)        // 360000
#define CBUF_OFF  (ZBAR_OFF  + BB*TT*NN)        // 600000

// ---------------------------------------------------------------------------
// Kernel 1: windowed time scans. Thread ranges:
//   A: xbar chunks           (b, chunk, i)  : 4*10*100 = 4000
//   B: zfilt+zbar chunks     (b, chunk, j)  : 4*10*200 = 8000
//   C: c = post*(G+coeff)    (b, chunk, j)  : 4*10*200 = 8000  (reverse filter)
// Channel index fastest -> coalesced loads/stores.
// ---------------------------------------------------------------------------
__global__ void scan_kernel(const float* __restrict__ v,
                            const float* __restrict__ z,
                            const float* __restrict__ x,
                            const float* __restrict__ error1,
                            const float* __restrict__ error2,
                            const float* __restrict__ w_out,
                            float* __restrict__ ws) {
    int tid = blockIdx.x * blockDim.x + threadIdx.x;
    float* xbar  = ws + XBAR_OFF;
    float* zfilt = ws + ZFILT_OFF;
    float* zbar  = ws + ZBAR_OFF;
    float* cbuf  = ws + CBUF_OFF;

    const int nA = BB * NCHK * NINN;
    const int nB = BB * NCHK * NN;

    if (tid < nA) {
        int i = tid % NINN, r = tid / NINN;
        int chunk = r % NCHK, b = r / NCHK;
        int t0 = chunk * LCH;
        int tw = t0 - WARM; if (tw < 0) tw = 0;
        float acc = 0.f;
        for (int t = tw; t < t0; ++t)
            acc = DECAY * acc + x[(b * TT + t) * NINN + i];
        for (int t = t0; t < t0 + LCH; ++t) {
            int idx = (b * TT + t) * NINN + i;
            acc = DECAY * acc + x[idx];
            xbar[idx] = acc;
        }
    } else if (tid < nA + nB) {
        int u = tid - nA;
        int j = u % NN, r = u / NN;
        int chunk = r % NCHK, b = r / NCHK;
        int t0 = chunk * LCH;
        int tw = t0 - WARM; if (tw < 0) tw = 0;
        float acc = 0.f;
        for (int t = tw; t < t0; ++t)
            acc = DECAY * acc + z[(b * TT + t) * NN + j];
        for (int t = t0; t < t0 + LCH; ++t) {
            int idx = (b * TT + t) * NN + j;
            zbar[idx] = acc;            // z_bar[t] = zfilt[t-1] (0 at t=0)
            acc = DECAY * acc + z[idx];
            zfilt[idx] = acc;
        }
    } else if (tid < nA + 2 * nB) {
        int u = tid - nA - nB;
        int j = u % NN, r = u / NN;
        int chunk = r % NCHK, b = r / NCHK;
        int t0 = chunk * LCH, t1 = t0 + LCH - 1;
        int te = t1 + WARM; if (te > TT - 1) te = TT - 1;

        float wj[KK];
        #pragma unroll
        for (int k = 0; k < KK; ++k) wj[k] = w_out[j * KK + k];
        float coeff = (REGC / (float)(BB * TT)) * error2[j];

        // reverse filter of learning signal: G[t] = L[t] + 0.8*G[t+1]
        float G = 0.f;
        for (int t = te; t > t1; --t) {
            const float* e = error1 + (b * TT + t) * KK;
            float L = 0.f;
            #pragma unroll
            for (int k = 0; k < KK; ++k) L += e[k] * wj[k];
            G = DECAY * G + L;
        }
        for (int t = t1; t >= t0; --t) {
            const float* e = error1 + (b * TT + t) * KK;
            float L = 0.f;
            #pragma unroll
            for (int k = 0; k < KK; ++k) L += e[k] * wj[k];
            G = DECAY * G + L;
            // refractory: ref[t] > 0 iff any spike in z[t-4 .. t-1]
            bool refr = false;
            #pragma unroll
            for (int d = 1; d <= 4; ++d) {
                int s = t - d;
                if (s >= 0 && z[(b * TT + s) * NN + j] > 0.f) refr = true;
            }
            float vv = v[(b * TT + t) * NN + j];
            float vs = (vv - THR) / THR;
            float psi = (DAMP / THR) * fmaxf(1.f - fabsf(vs), 0.f);
            float post = refr ? 0.f : psi;
            cbuf[(b * TT + t) * NN + j] = post * (G + coeff);
        }
    }
}

// ---------------------------------------------------------------------------
// Kernel 2: split-K contractions, atomicAdd into zeroed d_out.
//   Main: thread = (s, p, jq), j = 4*jq, float4 over j.
//         p<NIN -> dw_in row, else dw_rec row (diagonal never written).
//   Tail: thread = (s, j, k) -> dw_out.
// ---------------------------------------------------------------------------
__global__ void out_kernel(const float* __restrict__ error1,
                           const float* __restrict__ ws,
                           float* __restrict__ out) {
    int tid = blockIdx.x * blockDim.x + threadIdx.x;
    const float* xbar  = ws + XBAR_OFF;
    const float* zfilt = ws + ZFILT_OFF;
    const float* zbar  = ws + ZBAR_OFF;
    const float* cbuf  = ws + CBUF_OFF;

    const int JQ = NN / 4;                       // 50
    const int nMain = SKC * (NINN + NN) * JQ;    // 180000

    if (tid < nMain) {
        int jq = tid % JQ, r = tid / JQ;
        int p = r % (NINN + NN), s = r / (NINN + NN);
        int j0 = jq * 4;
        int btBase = s * KCH;
        float4 acc = make_float4(0.f, 0.f, 0.f, 0.f);
        if (p < NINN) {
            #pragma unroll 4
            for (int rr = 0; rr < KCH; ++rr) {
                int bt = btBase + rr;
                float a = xbar[bt * NINN + p];
                float4 cv = *(const float4*)(cbuf + bt * NN + j0);
                acc.x += a * cv.x; acc.y += a * cv.y;
                acc.z += a * cv.z; acc.w += a * cv.w;
            }
            float* o = out + p * NN + j0;
            atomicAdd(o + 0, acc.x); atomicAdd(o + 1, acc.y);
            atomicAdd(o + 2, acc.z); atomicAdd(o + 3, acc.w);
        } else {
            int i = p - NINN;
            #pragma unroll 4
            for (int rr = 0; rr < KCH; ++rr) {
                int bt = btBase + rr;
                float a = zbar[bt * NN + i];
                float4 cv = *(const float4*)(cbuf + bt * NN + j0);
                acc.x += a * cv.x; acc.y += a * cv.y;
                acc.z += a * cv.z; acc.w += a * cv.w;
            }
            float* o = out + NINN * NN + i * NN + j0;
            if (j0 + 0 != i) atomicAdd(o + 0, acc.x);   // autapse: diag stays 0
            if (j0 + 1 != i) atomicAdd(o + 1, acc.y);
            if (j0 + 2 != i) atomicAdd(o + 2, acc.z);
            if (j0 + 3 != i) atomicAdd(o + 3, acc.w);
        }
    } else if (tid < nMain + SKC * NN * KK) {
        int u = tid - nMain;
        int k = u % KK, r = u / KK;
        int j = r % NN, s = r / NN;
        int btBase = s * KCH;
        float acc = 0.f;
        #pragma unroll 4
        for (int rr = 0; rr < KCH; ++rr) {
            int bt = btBase + rr;
            acc += zfilt[bt * NN + j] * error1[bt * KK + k];
        }
        atomicAdd(out + NINN * NN + NN * NN + j * KK + k, acc);
    }
}

extern "C" void kernel_launch(void* const* d_in, const int* in_sizes, int n_in,
                              void* d_out, int out_size, void* d_ws, size_t ws_size,
                              hipStream_t stream) {
    const float* v  = (const float*)d_in[0];
    const float* z  = (const float*)d_in[1];
    const float* x  = (const float*)d_in[2];
    const float* e1 = (const float*)d_in[3];
    const float* e2 = (const float*)d_in[4];
    const float* wo = (const float*)d_in[5];
    float* out = (float*)d_out;
    float* ws  = (float*)d_ws;

    // out accumulated via atomics -> zero it first (capturable memset node)
    hipMemsetAsync(out, 0, (size_t)out_size * sizeof(float), stream);

    int nScan = BB * NCHK * NINN + 2 * BB * NCHK * NN;   // 20000
    scan_kernel<<<(nScan + 255) / 256, 256, 0, stream>>>(v, z, x, e1, e2, wo, ws);

    int nOut = SKC * (NINN + NN) * (NN / 4) + SKC * NN * KK;  // 204000
    out_kernel<<<(nOut + 255) / 256, 256, 0, stream>>>(e1, ws, out);
}

// Round 3
// 105.030 us; speedup vs baseline: 3.3819x; 1.3963x over previous
//
#include <hip/hip_runtime.h>

// Problem constants (fixed by setup_inputs)
#define BB    4
#define TT    300
#define NN    200
#define NINN  100
#define KK    10
#define DECAY 0.8f
#define THR   0.6f
#define DAMP  0.3f

// Scan chunking: fixed-length chunks, fixed warm-up -> compile-time trip
// counts so the compiler fully unrolls and batches loads.
#define LCH   20
#define NCHK  (TT / LCH)      // 15
#define WARM  48              // 0.8^48 * 5 ~ 1e-4, negligible vs 0.115 thr

// Contraction split-K
#define SK    24
#define KCH   (BB * TT / SK)  // 50

// ws layout (floats)
#define XBAR_OFF  0
#define ZFILT_OFF (BB*TT*NINN)                  // 120000
#define ZBAR_OFF  (ZFILT_OFF + BB*TT*NN)        // 360000
#define CBUF_OFF  (ZBAR_OFF  + BB*TT*NN)        // 600000
#define GBAR_OFF  (CBUF_OFF  + BB*TT*NN)        // 840000 (+12000)

// K1 thread ranges (each base multiple of 256 -> no wave straddle)
#define R_A_BASE  0
#define R_A_N     (BB*NCHK*NINN)     // 6000
#define R_B_BASE  6144
#define R_B_N     (BB*NCHK*NN)       // 12000
#define R_G_BASE  18176
#define R_G_N     (BB*NCHK*KK)       // 600
#define R_Z_BASE  18944
#define R_Z_N     15500              // 62000 floats / 4 (float4 zero of out)
#define K1_TOTAL  (R_Z_BASE + R_Z_N) // 34444

// ---------------------------------------------------------------------------
// Kernel 1: forward scans (xbar, zfilt/zbar), reverse scan of error1 (Gbar),
// and zeroing of d_out. All loops fully unrolled, loads batched.
// ---------------------------------------------------------------------------
__global__ void scan_kernel(const float* __restrict__ z,
                            const float* __restrict__ x,
                            const float* __restrict__ error1,
                            float* __restrict__ ws,
                            float* __restrict__ out) {
    int tid = blockIdx.x * blockDim.x + threadIdx.x;
    float* xbar  = ws + XBAR_OFF;
    float* zfilt = ws + ZFILT_OFF;
    float* zbar  = ws + ZBAR_OFF;
    float* gbar  = ws + GBAR_OFF;

    if (tid < R_A_N) {
        // ---- xbar forward: one thread per (b, chunk, i) ----
        int i = tid % NINN, r = tid / NINN;
        int chunk = r % NCHK, b = r / NCHK;
        int t0 = chunk * LCH;
        const float* src = x + (size_t)b * TT * NINN + i;
        float acc = 0.f;
        #pragma unroll
        for (int d = WARM; d >= 1; --d) {
            int t = t0 - d;
            int tc = t < 0 ? 0 : t;
            float val = src[tc * NINN];
            acc = DECAY * acc + (t < 0 ? 0.f : val);
        }
        float vals[LCH];
        #pragma unroll
        for (int tt = 0; tt < LCH; ++tt) vals[tt] = src[(t0 + tt) * NINN];
        #pragma unroll
        for (int tt = 0; tt < LCH; ++tt) { acc = DECAY * acc + vals[tt]; vals[tt] = acc; }
        float* dst = xbar + (size_t)b * TT * NINN + i;
        #pragma unroll
        for (int tt = 0; tt < LCH; ++tt) dst[(t0 + tt) * NINN] = vals[tt];
    } else if (tid >= R_B_BASE && tid < R_B_BASE + R_B_N) {
        // ---- zfilt/zbar forward: one thread per (b, chunk, j) ----
        int u = tid - R_B_BASE;
        int j = u % NN, r = u / NN;
        int chunk = r % NCHK, b = r / NCHK;
        int t0 = chunk * LCH;
        const float* src = z + (size_t)b * TT * NN + j;
        float acc = 0.f;
        #pragma unroll
        for (int d = WARM; d >= 1; --d) {
            int t = t0 - d;
            int tc = t < 0 ? 0 : t;
            float val = src[tc * NN];
            acc = DECAY * acc + (t < 0 ? 0.f : val);
        }
        float zv[LCH], pre[LCH];
        #pragma unroll
        for (int tt = 0; tt < LCH; ++tt) zv[tt] = src[(t0 + tt) * NN];
        #pragma unroll
        for (int tt = 0; tt < LCH; ++tt) {
            pre[tt] = acc;                      // zbar[t] = zfilt[t-1]
            acc = DECAY * acc + zv[tt];
            zv[tt] = acc;                       // zfilt[t]
        }
        float* dzb = zbar  + (size_t)b * TT * NN + j;
        float* dzf = zfilt + (size_t)b * TT * NN + j;
        #pragma unroll
        for (int tt = 0; tt < LCH; ++tt) dzb[(t0 + tt) * NN] = pre[tt];
        #pragma unroll
        for (int tt = 0; tt < LCH; ++tt) dzf[(t0 + tt) * NN] = zv[tt];
    } else if (tid >= R_G_BASE && tid < R_G_BASE + R_G_N) {
        // ---- Gbar reverse filter of error1: one thread per (b, chunk, k) ----
        int u = tid - R_G_BASE;
        int k = u % KK, r = u / KK;
        int chunk = r % NCHK, b = r / NCHK;
        int t0 = chunk * LCH, t1 = t0 + LCH - 1;
        const float* src = error1 + (size_t)b * TT * KK + k;
        float G = 0.f;
        #pragma unroll
        for (int d = WARM; d >= 1; --d) {
            int t = t1 + d;
            int tc = t > TT - 1 ? TT - 1 : t;
            float val = src[tc * KK];
            G = DECAY * G + (t > TT - 1 ? 0.f : val);
        }
        float ev[LCH];
        #pragma unroll
        for (int tt = 0; tt < LCH; ++tt) ev[tt] = src[(t1 - tt) * KK];
        float* dst = gbar + (size_t)b * TT * KK + k;
        #pragma unroll
        for (int tt = 0; tt < LCH; ++tt) {
            G = DECAY * G + ev[tt];             // Gbar[t] = e[t] + 0.8*Gbar[t+1]
            dst[(t1 - tt) * KK] = G;
        }
    } else if (tid >= R_Z_BASE && tid < R_Z_BASE + R_Z_N) {
        // ---- zero d_out (62000 floats) for K3 atomics ----
        int u = tid - R_Z_BASE;
        ((float4*)out)[u] = make_float4(0.f, 0.f, 0.f, 0.f);
    }
}

// ---------------------------------------------------------------------------
// Kernel 2: c[b,t,j] = post_term * (sum_k Gbar[b,t,k]*w_out[j,k] + coeff[j]).
// Fully parallel, one thread per element.
// ---------------------------------------------------------------------------
__global__ void c_kernel(const float* __restrict__ v,
                         const float* __restrict__ z,
                         const float* __restrict__ error2,
                         const float* __restrict__ w_out,
                         float* __restrict__ ws) {
    int tid = blockIdx.x * blockDim.x + threadIdx.x;
    if (tid >= BB * TT * NN) return;
    const float* gbar = ws + GBAR_OFF;
    float* cbuf = ws + CBUF_OFF;

    int j = tid % NN, bt = tid / NN;
    int t = bt % TT, b = bt / TT;

    float Ldot = 0.f;
    #pragma unroll
    for (int k = 0; k < KK; ++k)
        Ldot += gbar[bt * KK + k] * w_out[j * KK + k];
    float coeff = 0.25f * error2[j];            // REG/(B*T) = 300/1200

    // refractory: ref[t] > 0 iff any spike in z[t-4 .. t-1]
    bool refr = false;
    #pragma unroll
    for (int d = 1; d <= 4; ++d) {
        int s = t - d;
        int sc = s < 0 ? 0 : s;
        float zv = z[(b * TT + sc) * NN + j];
        if (s >= 0 && zv > 0.f) refr = true;
    }
    float vv = v[bt * NN + j];
    float vs = (vv - THR) / THR;
    float psi = (DAMP / THR) * fmaxf(1.f - fabsf(vs), 0.f);
    cbuf[bt * NN + j] = (refr ? 0.f : psi) * (Ldot + coeff);
}

// ---------------------------------------------------------------------------
// Kernel 3: contractions. Main: 4p x 4j register tile per thread, split-K=24,
// atomicAdd into zeroed out. Tail: dw_out.
// ---------------------------------------------------------------------------
#define R3_MAIN_N  (SK * 75 * 50)     // 90000
#define R3_TAIL_BASE 90112
#define R3_TAIL_N  (SK * NN * KK)     // 48000

__global__ void out_kernel(const float* __restrict__ error1,
                           const float* __restrict__ ws,
                           float* __restrict__ out) {
    int tid = blockIdx.x * blockDim.x + threadIdx.x;
    const float* xbar  = ws + XBAR_OFF;
    const float* zfilt = ws + ZFILT_OFF;
    const float* zbar  = ws + ZBAR_OFF;
    const float* cbuf  = ws + CBUF_OFF;

    if (tid < R3_MAIN_N) {
        int jq = tid % 50, r = tid / 50;
        int pg = r % 75, s = r / 75;
        int j0 = jq * 4, p0 = pg * 4;
        int btBase = s * KCH;

        bool isrec = (p0 >= NINN);
        const float* A = isrec ? (zbar + (p0 - NINN)) : (xbar + p0);
        int lda = isrec ? NN : NINN;

        float4 acc0 = make_float4(0,0,0,0), acc1 = acc0, acc2 = acc0, acc3 = acc0;
        #pragma unroll 10
        for (int rr = 0; rr < KCH; ++rr) {
            int bt = btBase + rr;
            float4 av = *(const float4*)(A + (size_t)bt * lda);
            float4 cv = *(const float4*)(cbuf + (size_t)bt * NN + j0);
            acc0.x += av.x * cv.x; acc0.y += av.x * cv.y; acc0.z += av.x * cv.z; acc0.w += av.x * cv.w;
            acc1.x += av.y * cv.x; acc1.y += av.y * cv.y; acc1.z += av.y * cv.z; acc1.w += av.y * cv.w;
            acc2.x += av.z * cv.x; acc2.y += av.z * cv.y; acc2.z += av.z * cv.z; acc2.w += av.z * cv.w;
            acc3.x += av.w * cv.x; acc3.y += av.w * cv.y; acc3.z += av.w * cv.z; acc3.w += av.w * cv.w;
        }
        float accs[4][4] = {
            {acc0.x, acc0.y, acc0.z, acc0.w},
            {acc1.x, acc1.y, acc1.z, acc1.w},
            {acc2.x, acc2.y, acc2.z, acc2.w},
            {acc3.x, acc3.y, acc3.z, acc3.w}};
        if (!isrec) {
            float* o = out + (size_t)p0 * NN + j0;
            #pragma unroll
            for (int a = 0; a < 4; ++a)
                #pragma unroll
                for (int bb = 0; bb < 4; ++bb)
                    atomicAdd(o + a * NN + bb, accs[a][bb]);
        } else {
            int i0 = p0 - NINN;
            float* o = out + NINN * NN + (size_t)i0 * NN + j0;
            #pragma unroll
            for (int a = 0; a < 4; ++a)
                #pragma unroll
                for (int bb = 0; bb < 4; ++bb)
                    if (i0 + a != j0 + bb)          // autapse diag stays 0
                        atomicAdd(o + a * NN + bb, accs[a][bb]);
        }
    } else if (tid >= R3_TAIL_BASE && tid < R3_TAIL_BASE + R3_TAIL_N) {
        int u = tid - R3_TAIL_BASE;
        int k = u % KK, r = u / KK;
        int j = r % NN, s = r / NN;
        int btBase = s * KCH;
        float acc = 0.f;
        #pragma unroll 10
        for (int rr = 0; rr < KCH; ++rr) {
            int bt = btBase + rr;
            acc += zfilt[bt * NN + j] * error1[bt * KK + k];
        }
        atomicAdd(out + NINN * NN + NN * NN + j * KK + k, acc);
    }
}

extern "C" void kernel_launch(void* const* d_in, const int* in_sizes, int n_in,
                              void* d_out, int out_size, void* d_ws, size_t ws_size,
                              hipStream_t stream) {
    const float* v  = (const float*)d_in[0];
    const float* z  = (const float*)d_in[1];
    const float* x  = (const float*)d_in[2];
    const float* e1 = (const float*)d_in[3];
    const float* e2 = (const float*)d_in[4];
    const float* wo = (const float*)d_in[5];
    float* out = (float*)d_out;
    float* ws  = (float*)d_ws;

    scan_kernel<<<(K1_TOTAL + 255) / 256, 256, 0, stream>>>(z, x, e1, ws, out);

    c_kernel<<<(BB * TT * NN + 255) / 256, 256, 0, stream>>>(v, z, e2, wo, ws);

    int n3 = R3_TAIL_BASE + R3_TAIL_N;
    out_kernel<<<(n3 + 255) / 256, 256, 0, stream>>>(e1, ws, out);
}

// Round 4
// 87.482 us; speedup vs baseline: 4.0602x; 1.2006x over previous
//
#include <hip/hip_runtime.h>

// Problem constants (fixed by setup_inputs)
#define BB    4
#define TT    300
#define NN    200
#define NINN  100
#define KK    10
#define DECAY 0.8f
#define THR   0.6f
#define DAMP  0.3f

// Scan chunking: compile-time trip counts (full unroll, batched loads).
#define LCH   20
#define NCHK  (TT / LCH)      // 15
#define WARM  48              // 0.8^48*5 ~ 1e-4 << 0.115 threshold

// ws layout (floats)
#define XBAR_OFF  0
#define ZFILT_OFF (BB*TT*NINN)                  // 120000
#define ZBAR_OFF  (ZFILT_OFF + BB*TT*NN)        // 360000
#define CBUF_OFF  (ZBAR_OFF  + BB*TT*NN)        // 600000
#define GBAR_OFF  (CBUF_OFF  + BB*TT*NN)        // 840000 (+12000)

// K1 thread ranges (bases multiple of 256 -> no wave straddle)
#define R_A_N     (BB*NCHK*NINN)     // 6000
#define R_B_BASE  6144
#define R_B_N     (BB*NCHK*NN)       // 12000
#define R_G_BASE  18176
#define R_G_N     (BB*NCHK*KK)       // 600
#define R_Z_BASE  18944
#define R_Z_N     500                // zero dw_out region (2000 floats, float4)
#define K1_TOTAL  (R_Z_BASE + R_Z_N)

// ---------------------------------------------------------------------------
// Kernel 1: forward scans (xbar, zfilt/zbar), reverse scan of error1 (Gbar),
// zero the dw_out region (for K3's small atomic tail).
// ---------------------------------------------------------------------------
__global__ void scan_kernel(const float* __restrict__ z,
                            const float* __restrict__ x,
                            const float* __restrict__ error1,
                            float* __restrict__ ws,
                            float* __restrict__ out) {
    int tid = blockIdx.x * blockDim.x + threadIdx.x;
    float* xbar  = ws + XBAR_OFF;
    float* zfilt = ws + ZFILT_OFF;
    float* zbar  = ws + ZBAR_OFF;
    float* gbar  = ws + GBAR_OFF;

    if (tid < R_A_N) {
        int i = tid % NINN, r = tid / NINN;
        int chunk = r % NCHK, b = r / NCHK;
        int t0 = chunk * LCH;
        const float* src = x + (size_t)b * TT * NINN + i;
        float acc = 0.f;
        #pragma unroll
        for (int d = WARM; d >= 1; --d) {
            int t = t0 - d;
            int tc = t < 0 ? 0 : t;
            float val = src[tc * NINN];
            acc = DECAY * acc + (t < 0 ? 0.f : val);
        }
        float vals[LCH];
        #pragma unroll
        for (int tt = 0; tt < LCH; ++tt) vals[tt] = src[(t0 + tt) * NINN];
        #pragma unroll
        for (int tt = 0; tt < LCH; ++tt) { acc = DECAY * acc + vals[tt]; vals[tt] = acc; }
        float* dst = xbar + (size_t)b * TT * NINN + i;
        #pragma unroll
        for (int tt = 0; tt < LCH; ++tt) dst[(t0 + tt) * NINN] = vals[tt];
    } else if (tid >= R_B_BASE && tid < R_B_BASE + R_B_N) {
        int u = tid - R_B_BASE;
        int j = u % NN, r = u / NN;
        int chunk = r % NCHK, b = r / NCHK;
        int t0 = chunk * LCH;
        const float* src = z + (size_t)b * TT * NN + j;
        float acc = 0.f;
        #pragma unroll
        for (int d = WARM; d >= 1; --d) {
            int t = t0 - d;
            int tc = t < 0 ? 0 : t;
            float val = src[tc * NN];
            acc = DECAY * acc + (t < 0 ? 0.f : val);
        }
        float zv[LCH], pre[LCH];
        #pragma unroll
        for (int tt = 0; tt < LCH; ++tt) zv[tt] = src[(t0 + tt) * NN];
        #pragma unroll
        for (int tt = 0; tt < LCH; ++tt) {
            pre[tt] = acc;                      // zbar[t] = zfilt[t-1]
            acc = DECAY * acc + zv[tt];
            zv[tt] = acc;                       // zfilt[t]
        }
        float* dzb = zbar  + (size_t)b * TT * NN + j;
        float* dzf = zfilt + (size_t)b * TT * NN + j;
        #pragma unroll
        for (int tt = 0; tt < LCH; ++tt) dzb[(t0 + tt) * NN] = pre[tt];
        #pragma unroll
        for (int tt = 0; tt < LCH; ++tt) dzf[(t0 + tt) * NN] = zv[tt];
    } else if (tid >= R_G_BASE && tid < R_G_BASE + R_G_N) {
        int u = tid - R_G_BASE;
        int k = u % KK, r = u / KK;
        int chunk = r % NCHK, b = r / NCHK;
        int t0 = chunk * LCH, t1 = t0 + LCH - 1;
        const float* src = error1 + (size_t)b * TT * KK + k;
        float G = 0.f;
        #pragma unroll
        for (int d = WARM; d >= 1; --d) {
            int t = t1 + d;
            int tc = t > TT - 1 ? TT - 1 : t;
            float val = src[tc * KK];
            G = DECAY * G + (t > TT - 1 ? 0.f : val);
        }
        float ev[LCH];
        #pragma unroll
        for (int tt = 0; tt < LCH; ++tt) ev[tt] = src[(t1 - tt) * KK];
        float* dst = gbar + (size_t)b * TT * KK + k;
        #pragma unroll
        for (int tt = 0; tt < LCH; ++tt) {
            G = DECAY * G + ev[tt];             // Gbar[t] = e[t] + 0.8*Gbar[t+1]
            dst[(t1 - tt) * KK] = G;
        }
    } else if (tid >= R_Z_BASE && tid < R_Z_BASE + R_Z_N) {
        int u = tid - R_Z_BASE;
        ((float4*)(out + NINN * NN + NN * NN))[u] = make_float4(0.f, 0.f, 0.f, 0.f);
    }
}

// ---------------------------------------------------------------------------
// Kernel 2: c[b,t,j] = post_term * (sum_k Gbar[b,t,k]*w_out[j,k] + coeff[j]).
// (unchanged from round 3)
// ---------------------------------------------------------------------------
__global__ void c_kernel(const float* __restrict__ v,
                         const float* __restrict__ z,
                         const float* __restrict__ error2,
                         const float* __restrict__ w_out,
                         float* __restrict__ ws) {
    int tid = blockIdx.x * blockDim.x + threadIdx.x;
    if (tid >= BB * TT * NN) return;
    const float* gbar = ws + GBAR_OFF;
    float* cbuf = ws + CBUF_OFF;

    int j = tid % NN, bt = tid / NN;
    int t = bt % TT, b = bt / TT;

    float Ldot = 0.f;
    #pragma unroll
    for (int k = 0; k < KK; ++k)
        Ldot += gbar[bt * KK + k] * w_out[j * KK + k];
    float coeff = 0.25f * error2[j];            // REG/(B*T) = 300/1200

    bool refr = false;
    #pragma unroll
    for (int d = 1; d <= 4; ++d) {
        int s = t - d;
        int sc = s < 0 ? 0 : s;
        float zv = z[(b * TT + sc) * NN + j];
        if (s >= 0 && zv > 0.f) refr = true;
    }
    float vv = v[bt * NN + j];
    float vs = (vv - THR) / THR;
    float psi = (DAMP / THR) * fmaxf(1.f - fabsf(vs), 0.f);
    cbuf[bt * NN + j] = (refr ? 0.f : psi) * (Ldot + coeff);
}

// ---------------------------------------------------------------------------
// Kernel 3: atomic-free blocked contraction.
//   Blocks 0..299: output tile 4p x 64j. 256 threads = 16 K-groups x 16 jq;
//     each thread 4x4 register tile over 75 bt; LDS reduce over K-groups;
//     coalesced direct store (rec diagonal stored as 0).
//   Blocks 300..346: dw_out, split-K=6 atomics (12k atomics, region zeroed).
// ---------------------------------------------------------------------------
#define SKB 16
#define KC3 (BB * TT / SKB)    // 75
#define PT  4
#define JT  64

__global__ void out_kernel(const float* __restrict__ error1,
                           const float* __restrict__ ws,
                           float* __restrict__ out) {
    __shared__ float red[SKB * PT * JT];   // 16 KB
    int bid = blockIdx.x;
    int tid = threadIdx.x;
    const float* xbar  = ws + XBAR_OFF;
    const float* zfilt = ws + ZFILT_OFF;
    const float* zbar  = ws + ZBAR_OFF;
    const float* cbuf  = ws + CBUF_OFF;

    if (bid < 300) {
        int pt = bid >> 2;                 // 0..74
        int jt = bid & 3;                  // 0..3
        int p0 = pt * PT;
        int j0 = jt * JT;
        int W = NN - j0; if (W > JT) W = JT;     // 64,64,64,8
        int jq = tid & 15;
        int s  = tid >> 4;

        if (jq * 4 < W) {
            bool isrec = (p0 >= NINN);     // PT=4 divides 100 -> uniform per block
            const float* A = isrec ? (zbar + (p0 - NINN)) : (xbar + p0);
            int lda = isrec ? NN : NINN;
            const float* C = cbuf + j0 + jq * 4;
            int bt0 = s * KC3;
            float acc[4][4];
            #pragma unroll
            for (int a = 0; a < 4; ++a)
                #pragma unroll
                for (int c = 0; c < 4; ++c) acc[a][c] = 0.f;
            #pragma unroll 5
            for (int rr = 0; rr < KC3; ++rr) {
                int bt = bt0 + rr;
                float4 av = *(const float4*)(A + (size_t)bt * lda);
                float4 cv = *(const float4*)(C + (size_t)bt * NN);
                float am[4] = {av.x, av.y, av.z, av.w};
                float cm[4] = {cv.x, cv.y, cv.z, cv.w};
                #pragma unroll
                for (int a = 0; a < 4; ++a)
                    #pragma unroll
                    for (int c = 0; c < 4; ++c) acc[a][c] += am[a] * cm[c];
            }
            float* dst = red + s * (PT * JT) + jq * 4;
            #pragma unroll
            for (int a = 0; a < 4; ++a)
                *(float4*)(dst + a * JT) =
                    make_float4(acc[a][0], acc[a][1], acc[a][2], acc[a][3]);
        }
        __syncthreads();

        int o = tid;                       // p_local*64 + j_local
        int pl = o >> 6, jl = o & 63;
        if (jl < W) {
            float sum = 0.f;
            #pragma unroll
            for (int s2 = 0; s2 < SKB; ++s2) sum += red[s2 * (PT * JT) + o];
            int row = p0 + pl;
            int j = j0 + jl;
            if (row < NINN) {
                out[row * NN + j] = sum;
            } else {
                int i = row - NINN;
                out[NINN * NN + i * NN + j] = (i == j) ? 0.f : sum;
            }
        }
    } else {
        int u = (bid - 300) * 256 + tid;
        if (u < 6 * NN * KK) {
            int jk = u % (NN * KK);
            int s = u / (NN * KK);         // 0..5
            int j = jk % NN;               // lanes -> coalesced zfilt
            int k = jk / NN;
            int bt0 = s * 200;
            float acc = 0.f;
            #pragma unroll 8
            for (int rr = 0; rr < 200; ++rr) {
                int bt = bt0 + rr;
                acc += zfilt[bt * NN + j] * error1[bt * KK + k];
            }
            atomicAdd(out + NINN * NN + NN * NN + j * KK + k, acc);
        }
    }
}

extern "C" void kernel_launch(void* const* d_in, const int* in_sizes, int n_in,
                              void* d_out, int out_size, void* d_ws, size_t ws_size,
                              hipStream_t stream) {
    const float* v  = (const float*)d_in[0];
    const float* z  = (const float*)d_in[1];
    const float* x  = (const float*)d_in[2];
    const float* e1 = (const float*)d_in[3];
    const float* e2 = (const float*)d_in[4];
    const float* wo = (const float*)d_in[5];
    float* out = (float*)d_out;
    float* ws  = (float*)d_ws;

    scan_kernel<<<(K1_TOTAL + 255) / 256, 256, 0, stream>>>(z, x, e1, ws, out);

    c_kernel<<<(BB * TT * NN + 255) / 256, 256, 0, stream>>>(v, z, e2, wo, ws);

    out_kernel<<<347, 256, 0, stream>>>(e1, ws, out);
}

// Round 5
// 87.178 us; speedup vs baseline: 4.0744x; 1.0035x over previous
//
#include <hip/hip_runtime.h>

// Problem constants (fixed by setup_inputs)
#define BB    4
#define TT    300
#define NN    200
#define NINN  100
#define KK    10
#define DECAY 0.8f
#define THR   0.6f
#define DAMP  0.3f

// Scan chunking: compile-time trip counts (full unroll, batched loads).
#define LCH   20
#define NCHK  (TT / LCH)      // 15
#define WARM  48              // 0.8^48*5 ~ 1e-4 << 0.115 threshold

// ws layout (floats)
#define XBAR_OFF  0
#define ZFILT_OFF (BB*TT*NINN)                  // 120000
#define ZBAR_OFF  (ZFILT_OFF + BB*TT*NN)        // 360000
#define CBUF_OFF  (ZBAR_OFF  + BB*TT*NN)        // 600000
#define GBAR_OFF  (CBUF_OFF  + BB*TT*NN)        // 840000 (+12000)

// K1 thread ranges (bases multiple of 256 -> no wave straddle)
#define R_A_N     (BB*NCHK*NINN)     // 6000
#define R_B_BASE  6144
#define R_B_N     (BB*NCHK*NN)       // 12000
#define R_G_BASE  18176
#define R_G_N     (BB*NCHK*KK)       // 600
#define R_Z_BASE  18944
#define R_Z_N     500                // zero dw_out region (2000 floats, float4)
#define K1_TOTAL  (R_Z_BASE + R_Z_N)

// ---------------------------------------------------------------------------
// Kernel 1: forward scans (xbar, zfilt/zbar), reverse scan of error1 (Gbar),
// zero the dw_out region (for K3's small atomic tail).  [unchanged]
// ---------------------------------------------------------------------------
__global__ void scan_kernel(const float* __restrict__ z,
                            const float* __restrict__ x,
                            const float* __restrict__ error1,
                            float* __restrict__ ws,
                            float* __restrict__ out) {
    int tid = blockIdx.x * blockDim.x + threadIdx.x;
    float* xbar  = ws + XBAR_OFF;
    float* zfilt = ws + ZFILT_OFF;
    float* zbar  = ws + ZBAR_OFF;
    float* gbar  = ws + GBAR_OFF;

    if (tid < R_A_N) {
        int i = tid % NINN, r = tid / NINN;
        int chunk = r % NCHK, b = r / NCHK;
        int t0 = chunk * LCH;
        const float* src = x + (size_t)b * TT * NINN + i;
        float acc = 0.f;
        #pragma unroll
        for (int d = WARM; d >= 1; --d) {
            int t = t0 - d;
            int tc = t < 0 ? 0 : t;
            float val = src[tc * NINN];
            acc = DECAY * acc + (t < 0 ? 0.f : val);
        }
        float vals[LCH];
        #pragma unroll
        for (int tt = 0; tt < LCH; ++tt) vals[tt] = src[(t0 + tt) * NINN];
        #pragma unroll
        for (int tt = 0; tt < LCH; ++tt) { acc = DECAY * acc + vals[tt]; vals[tt] = acc; }
        float* dst = xbar + (size_t)b * TT * NINN + i;
        #pragma unroll
        for (int tt = 0; tt < LCH; ++tt) dst[(t0 + tt) * NINN] = vals[tt];
    } else if (tid >= R_B_BASE && tid < R_B_BASE + R_B_N) {
        int u = tid - R_B_BASE;
        int j = u % NN, r = u / NN;
        int chunk = r % NCHK, b = r / NCHK;
        int t0 = chunk * LCH;
        const float* src = z + (size_t)b * TT * NN + j;
        float acc = 0.f;
        #pragma unroll
        for (int d = WARM; d >= 1; --d) {
            int t = t0 - d;
            int tc = t < 0 ? 0 : t;
            float val = src[tc * NN];
            acc = DECAY * acc + (t < 0 ? 0.f : val);
        }
        float zv[LCH], pre[LCH];
        #pragma unroll
        for (int tt = 0; tt < LCH; ++tt) zv[tt] = src[(t0 + tt) * NN];
        #pragma unroll
        for (int tt = 0; tt < LCH; ++tt) {
            pre[tt] = acc;                      // zbar[t] = zfilt[t-1]
            acc = DECAY * acc + zv[tt];
            zv[tt] = acc;                       // zfilt[t]
        }
        float* dzb = zbar  + (size_t)b * TT * NN + j;
        float* dzf = zfilt + (size_t)b * TT * NN + j;
        #pragma unroll
        for (int tt = 0; tt < LCH; ++tt) dzb[(t0 + tt) * NN] = pre[tt];
        #pragma unroll
        for (int tt = 0; tt < LCH; ++tt) dzf[(t0 + tt) * NN] = zv[tt];
    } else if (tid >= R_G_BASE && tid < R_G_BASE + R_G_N) {
        int u = tid - R_G_BASE;
        int k = u % KK, r = u / KK;
        int chunk = r % NCHK, b = r / NCHK;
        int t0 = chunk * LCH, t1 = t0 + LCH - 1;
        const float* src = error1 + (size_t)b * TT * KK + k;
        float G = 0.f;
        #pragma unroll
        for (int d = WARM; d >= 1; --d) {
            int t = t1 + d;
            int tc = t > TT - 1 ? TT - 1 : t;
            float val = src[tc * KK];
            G = DECAY * G + (t > TT - 1 ? 0.f : val);
        }
        float ev[LCH];
        #pragma unroll
        for (int tt = 0; tt < LCH; ++tt) ev[tt] = src[(t1 - tt) * KK];
        float* dst = gbar + (size_t)b * TT * KK + k;
        #pragma unroll
        for (int tt = 0; tt < LCH; ++tt) {
            G = DECAY * G + ev[tt];             // Gbar[t] = e[t] + 0.8*Gbar[t+1]
            dst[(t1 - tt) * KK] = G;
        }
    } else if (tid >= R_Z_BASE && tid < R_Z_BASE + R_Z_N) {
        int u = tid - R_Z_BASE;
        ((float4*)(out + NINN * NN + NN * NN))[u] = make_float4(0.f, 0.f, 0.f, 0.f);
    }
}

// ---------------------------------------------------------------------------
// Kernel 2 (REWRITTEN): one thread per (bt, 4-wide j), all float4.
// c[bt,j] = post_term * (sum_k Gbar[bt,k]*w_out[j,k] + 0.25*error2[j]).
// 60000 threads; gbar/w_out loads amortized over 4 outputs.
// ---------------------------------------------------------------------------
__global__ void c_kernel(const float* __restrict__ v,
                         const float* __restrict__ z,
                         const float* __restrict__ error2,
                         const float* __restrict__ w_out,
                         float* __restrict__ ws) {
    int tid = blockIdx.x * blockDim.x + threadIdx.x;
    if (tid >= BB * TT * NN / 4) return;        // 60000
    const float* gbar = ws + GBAR_OFF;
    float* cbuf = ws + CBUF_OFF;

    int jq = tid % (NN / 4), bt = tid / (NN / 4);
    int j0 = jq * 4;
    int t = bt % TT, b = bt / TT;

    float g[KK];
    #pragma unroll
    for (int k = 0; k < KK; ++k) g[k] = gbar[bt * KK + k];

    float Ld[4];
    #pragma unroll
    for (int a = 0; a < 4; ++a) {
        const float* wr = w_out + (j0 + a) * KK;
        float acc = 0.f;
        #pragma unroll
        for (int k = 0; k < KK; ++k) acc += g[k] * wr[k];
        Ld[a] = acc;
    }

    float4 e2 = *(const float4*)(error2 + j0);
    float co[4] = {0.25f * e2.x, 0.25f * e2.y, 0.25f * e2.z, 0.25f * e2.w};

    // refractory: ref[t] > 0 iff any spike in z[t-4 .. t-1]
    bool refr[4] = {false, false, false, false};
    #pragma unroll
    for (int d = 1; d <= 4; ++d) {
        int s = t - d;
        int sc = s < 0 ? 0 : s;
        float4 zv = *(const float4*)(z + ((size_t)b * TT + sc) * NN + j0);
        if (s >= 0) {
            if (zv.x > 0.f) refr[0] = true;
            if (zv.y > 0.f) refr[1] = true;
            if (zv.z > 0.f) refr[2] = true;
            if (zv.w > 0.f) refr[3] = true;
        }
    }

    float4 vv = *(const float4*)(v + (size_t)bt * NN + j0);
    float vm[4] = {vv.x, vv.y, vv.z, vv.w};
    float cm[4];
    #pragma unroll
    for (int a = 0; a < 4; ++a) {
        float vs = (vm[a] - THR) / THR;
        float psi = (DAMP / THR) * fmaxf(1.f - fabsf(vs), 0.f);
        cm[a] = (refr[a] ? 0.f : psi) * (Ld[a] + co[a]);
    }
    *(float4*)(cbuf + (size_t)bt * NN + j0) = make_float4(cm[0], cm[1], cm[2], cm[3]);
}

// ---------------------------------------------------------------------------
// Kernel 3: atomic-free blocked contraction.  [unchanged]
// ---------------------------------------------------------------------------
#define SKB 16
#define KC3 (BB * TT / SKB)    // 75
#define PT  4
#define JT  64

__global__ void out_kernel(const float* __restrict__ error1,
                           const float* __restrict__ ws,
                           float* __restrict__ out) {
    __shared__ float red[SKB * PT * JT];   // 16 KB
    int bid = blockIdx.x;
    int tid = threadIdx.x;
    const float* xbar  = ws + XBAR_OFF;
    const float* zfilt = ws + ZFILT_OFF;
    const float* zbar  = ws + ZBAR_OFF;
    const float* cbuf  = ws + CBUF_OFF;

    if (bid < 300) {
        int pt = bid >> 2;                 // 0..74
        int jt = bid & 3;                  // 0..3
        int p0 = pt * PT;
        int j0 = jt * JT;
        int W = NN - j0; if (W > JT) W = JT;     // 64,64,64,8
        int jq = tid & 15;
        int s  = tid >> 4;

        if (jq * 4 < W) {
            bool isrec = (p0 >= NINN);     // PT=4 divides 100 -> uniform per block
            const float* A = isrec ? (zbar + (p0 - NINN)) : (xbar + p0);
            int lda = isrec ? NN : NINN;
            const float* C = cbuf + j0 + jq * 4;
            int bt0 = s * KC3;
            float acc[4][4];
            #pragma unroll
            for (int a = 0; a < 4; ++a)
                #pragma unroll
                for (int c = 0; c < 4; ++c) acc[a][c] = 0.f;
            #pragma unroll 5
            for (int rr = 0; rr < KC3; ++rr) {
                int bt = bt0 + rr;
                float4 av = *(const float4*)(A + (size_t)bt * lda);
                float4 cv = *(const float4*)(C + (size_t)bt * NN);
                float am[4] = {av.x, av.y, av.z, av.w};
                float cm[4] = {cv.x, cv.y, cv.z, cv.w};
                #pragma unroll
                for (int a = 0; a < 4; ++a)
                    #pragma unroll
                    for (int c = 0; c < 4; ++c) acc[a][c] += am[a] * cm[c];
            }
            float* dst = red + s * (PT * JT) + jq * 4;
            #pragma unroll
            for (int a = 0; a < 4; ++a)
                *(float4*)(dst + a * JT) =
                    make_float4(acc[a][0], acc[a][1], acc[a][2], acc[a][3]);
        }
        __syncthreads();

        int o = tid;                       // p_local*64 + j_local
        int pl = o >> 6, jl = o & 63;
        if (jl < W) {
            float sum = 0.f;
            #pragma unroll
            for (int s2 = 0; s2 < SKB; ++s2) sum += red[s2 * (PT * JT) + o];
            int row = p0 + pl;
            int j = j0 + jl;
            if (row < NINN) {
                out[row * NN + j] = sum;
            } else {
                int i = row - NINN;
                out[NINN * NN + i * NN + j] = (i == j) ? 0.f : sum;
            }
        }
    } else {
        int u = (bid - 300) * 256 + tid;
        if (u < 6 * NN * KK) {
            int jk = u % (NN * KK);
            int s = u / (NN * KK);         // 0..5
            int j = jk % NN;               // lanes -> coalesced zfilt
            int k = jk / NN;
            int bt0 = s * 200;
            float acc = 0.f;
            #pragma unroll 8
            for (int rr = 0; rr < 200; ++rr) {
                int bt = bt0 + rr;
                acc += zfilt[bt * NN + j] * error1[bt * KK + k];
            }
            atomicAdd(out + NINN * NN + NN * NN + j * KK + k, acc);
        }
    }
}

extern "C" void kernel_launch(void* const* d_in, const int* in_sizes, int n_in,
                              void* d_out, int out_size, void* d_ws, size_t ws_size,
                              hipStream_t stream) {
    const float* v  = (const float*)d_in[0];
    const float* z  = (const float*)d_in[1];
    const float* x  = (const float*)d_in[2];
    const float* e1 = (const float*)d_in[3];
    const float* e2 = (const float*)d_in[4];
    const float* wo = (const float*)d_in[5];
    float* out = (float*)d_out;
    float* ws  = (float*)d_ws;

    scan_kernel<<<(K1_TOTAL + 255) / 256, 256, 0, stream>>>(z, x, e1, ws, out);

    c_kernel<<<(BB * TT * NN / 4 + 255) / 256, 256, 0, stream>>>(v, z, e2, wo, ws);

    out_kernel<<<347, 256, 0, stream>>>(e1, ws, out);
}